// Round 1
// baseline (5664.718 us; speedup 1.0000x reference)
//
#include <hip/hip_runtime.h>
#include <hip/hip_bf16.h>

// ---------------- constants ----------------
constexpr int S_   = 512;   // seq
constexpr int B_   = 4;     // batch
constexpr int NH_  = 12;    // heads
constexpr int DH_  = 64;    // head dim
constexpr int DM_  = 768;   // model dim
constexpr int DI_  = 3072;  // ffn inner
constexpr int V_   = 32000; // vocab
constexpr int M_   = S_ * B_;   // 2048 tokens

// ---------------- fp32 tiled GEMM: C[M,N] = A[M,K] @ B (+bias)(+relu) ----
// TB=false: B is [K,N] row-major.  TB=true: B is [N,K] row-major (C=A@B^T).
// EPI: 0 none, 1 +bias[n], 2 +bias[n] then relu.
// Requires M%128==0, N%128==0, K%16==0 (true for all call sites).
template<bool TB, int EPI>
__global__ __launch_bounds__(256) void gemm_k(const float* __restrict__ A,
                                              const float* __restrict__ Bm,
                                              const float* __restrict__ bias,
                                              float* __restrict__ C,
                                              int M, int N, int K) {
  __shared__ float As[16][128 + 4];
  __shared__ float Bs[16][128 + 4];
  const int tid = threadIdx.x;
  const int tx = tid & 15;   // n micro
  const int ty = tid >> 4;   // m micro
  const int m0 = blockIdx.y * 128;
  const int n0 = blockIdx.x * 128;

  float acc[8][8];
#pragma unroll
  for (int i = 0; i < 8; ++i)
#pragma unroll
    for (int j = 0; j < 8; ++j) acc[i][j] = 0.f;

  for (int k0 = 0; k0 < K; k0 += 16) {
    // A tile 128x16 -> As[k][m]
#pragma unroll
    for (int rep = 0; rep < 2; ++rep) {
      int f = tid + rep * 256;            // 0..511 float4
      int row = f >> 2, kq = f & 3;
      float4 av = *reinterpret_cast<const float4*>(&A[(size_t)(m0 + row) * K + k0 + kq * 4]);
      As[kq * 4 + 0][row] = av.x;
      As[kq * 4 + 1][row] = av.y;
      As[kq * 4 + 2][row] = av.z;
      As[kq * 4 + 3][row] = av.w;
    }
    if (!TB) {
#pragma unroll
      for (int rep = 0; rep < 2; ++rep) {
        int f = tid + rep * 256;          // 16 rows x 32 float4
        int row = f >> 5, nq = f & 31;
        float4 bv = *reinterpret_cast<const float4*>(&Bm[(size_t)(k0 + row) * N + n0 + nq * 4]);
        *reinterpret_cast<float4*>(&Bs[row][nq * 4]) = bv;
      }
    } else {
#pragma unroll
      for (int rep = 0; rep < 2; ++rep) {
        int f = tid + rep * 256;          // 128 n-rows x 4 float4
        int nr = f >> 2, kq = f & 3;
        float4 bv = *reinterpret_cast<const float4*>(&Bm[(size_t)(n0 + nr) * K + k0 + kq * 4]);
        Bs[kq * 4 + 0][nr] = bv.x;
        Bs[kq * 4 + 1][nr] = bv.y;
        Bs[kq * 4 + 2][nr] = bv.z;
        Bs[kq * 4 + 3][nr] = bv.w;
      }
    }
    __syncthreads();
#pragma unroll
    for (int kk = 0; kk < 16; ++kk) {
      float a[8], b[8];
#pragma unroll
      for (int j = 0; j < 4; ++j) { a[j] = As[kk][ty * 4 + j]; a[4 + j] = As[kk][ty * 4 + 64 + j]; }
#pragma unroll
      for (int j = 0; j < 4; ++j) { b[j] = Bs[kk][tx * 4 + j]; b[4 + j] = Bs[kk][tx * 4 + 64 + j]; }
#pragma unroll
      for (int i = 0; i < 8; ++i)
#pragma unroll
        for (int j = 0; j < 8; ++j) acc[i][j] = fmaf(a[i], b[j], acc[i][j]);
    }
    __syncthreads();
  }
#pragma unroll
  for (int i = 0; i < 8; ++i) {
    int m = m0 + ty * 4 + (i < 4 ? i : 64 + i - 4);
#pragma unroll
    for (int jh = 0; jh < 2; ++jh) {
      int nb = n0 + tx * 4 + jh * 64;
      float4 v;
      float* vp = &v.x;
#pragma unroll
      for (int j = 0; j < 4; ++j) {
        float x = acc[i][jh * 4 + j];
        if (EPI >= 1) x += bias[nb + j];
        if (EPI == 2) x = fmaxf(x, 0.f);
        vp[j] = x;
      }
      *reinterpret_cast<float4*>(&C[(size_t)m * N + nb]) = v;
    }
  }
}

// ---------------- embedding gather: h[t,:] = emb[idx[t],:] --------------
__global__ __launch_bounds__(256) void gather_k(const int* __restrict__ idx,
                                                const float* __restrict__ emb,
                                                float* __restrict__ h) {
  int t = blockIdx.x, tid = threadIdx.x;
  int row = idx[t];
  if (tid < 192) {
    float4 v = *reinterpret_cast<const float4*>(&emb[(size_t)row * DM_ + tid * 4]);
    *reinterpret_cast<float4*>(&h[(size_t)t * DM_ + tid * 4]) = v;
  }
}

// ---------------- positional embedding r[u,d], u in [0,2S) --------------
__global__ __launch_bounds__(256) void posemb_k(float* __restrict__ r) {
  int u = blockIdx.x, tid = threadIdx.x;
  float pos = (float)(S_ - u);
  for (int d = tid; d < DM_; d += 256) {
    int kidx = d < 384 ? d : d - 384;
    float invf = expf(-(float)kidx * (9.210340371976184f / 384.0f)); // 10000^(-2k/768)
    float arg = pos * invf;
    r[(size_t)u * DM_ + d] = (d < 384) ? sinf(arg) : cosf(arg);
  }
}

// ---------------- ef[t,n,s] = (q[t,n,:]+r_s_bias[l,n,:]) . seg_embed[l,s,n,:]
__global__ __launch_bounds__(256) void ef_k(const float* __restrict__ q,
                                            const float* __restrict__ rsb,
                                            const float* __restrict__ segemb,
                                            float* __restrict__ ef, int layer) {
  int id = blockIdx.x * 256 + threadIdx.x;     // t*24 + n*2 + s, total 49152
  int t = id / 24, rem = id % 24, n = rem >> 1, s = rem & 1;
  const float* qp = q + (size_t)t * DM_ + n * DH_;
  const float* rp = rsb + ((size_t)layer * NH_ + n) * DH_;
  const float* sp = segemb + (((size_t)layer * 2 + s) * NH_ + n) * DH_;
  float acc = 0.f;
#pragma unroll
  for (int d = 0; d < DH_; ++d) acc = fmaf(qp[d] + rp[d], sp[d], acc);
  ef[id] = acc;
}

// ---------------- fused attention scores (ac + rel-shifted bd + ef, mask)
// scores[bn][i][j] ; bn = b*NH + n
__global__ __launch_bounds__(256) void score_k(const float* __restrict__ q,
                                               const float* __restrict__ kb,
                                               const float* __restrict__ kr,
                                               const float* __restrict__ ef,
                                               const int* __restrict__ seg,
                                               const float* __restrict__ rwb_all,
                                               const float* __restrict__ rrb_all,
                                               float* __restrict__ scores, int layer) {
  const int jb = blockIdx.x, ib = blockIdx.y, bn = blockIdx.z;
  const int b = bn / NH_, n = bn % NH_;
  const int i0 = ib * 64, j0 = jb * 64;
  const int tid = threadIdx.x;
  float* out = scores + ((size_t)bn * S_ + i0) * S_ + j0;

  if (j0 > i0 + 63) {  // fully masked tile
    float4 neg = make_float4(-1e30f, -1e30f, -1e30f, -1e30f);
#pragma unroll
    for (int rep = 0; rep < 4; ++rep) {
      int f = tid + rep * 256;
      int row = f >> 4, c4 = f & 15;
      *reinterpret_cast<float4*>(&out[(size_t)row * S_ + c4 * 4]) = neg;
    }
    return;
  }

  __shared__ float q_s[64][68];
  __shared__ float k_s[64][68];
  __shared__ float kr_s[128][68];
  __shared__ float rwb_s[64], rrb_s[64];
  __shared__ float rwbk[64], rrbkr[128];
  __shared__ int segi[64], segj[64];

#pragma unroll
  for (int rep = 0; rep < 4; ++rep) {
    int f = tid + rep * 256;             // 1024 float4
    int row = f >> 4, dq = f & 15;
    float4 qv = *reinterpret_cast<const float4*>(&q[((size_t)(i0 + row) * B_ + b) * DM_ + n * DH_ + dq * 4]);
    *reinterpret_cast<float4*>(&q_s[row][dq * 4]) = qv;
    float4 kv = *reinterpret_cast<const float4*>(&kb[((size_t)(j0 + row) * B_ + b) * DM_ + n * DH_ + dq * 4]);
    *reinterpret_cast<float4*>(&k_s[row][dq * 4]) = kv;
  }
  int ubase = S_ + j0 - i0 - 63;         // >= 1 always
#pragma unroll
  for (int rep = 0; rep < 8; ++rep) {
    int f = tid + rep * 256;             // 2048 float4
    int row = f >> 4, dq = f & 15;
    int ur = ubase + row; ur = ur > 2 * S_ - 1 ? 2 * S_ - 1 : ur;  // clamp (unused rows)
    float4 v = *reinterpret_cast<const float4*>(&kr[(size_t)ur * DM_ + n * DH_ + dq * 4]);
    *reinterpret_cast<float4*>(&kr_s[row][dq * 4]) = v;
  }
  if (tid < 64)       rwb_s[tid]        = rwb_all[((size_t)layer * NH_ + n) * DH_ + tid];
  else if (tid < 128) rrb_s[tid - 64]   = rrb_all[((size_t)layer * NH_ + n) * DH_ + (tid - 64)];
  else if (tid < 192) segi[tid - 128]   = seg[(i0 + tid - 128) * B_ + b];
  else                segj[tid - 192]   = seg[(j0 + tid - 192) * B_ + b];
  __syncthreads();

  if (tid < 64) {
    float s = 0.f;
#pragma unroll
    for (int d = 0; d < 64; ++d) s = fmaf(rwb_s[d], k_s[tid][d], s);
    rwbk[tid] = s;
  } else if (tid < 192) {
    int u = tid - 64;
    float s = 0.f;
#pragma unroll
    for (int d = 0; d < 64; ++d) s = fmaf(rrb_s[d], kr_s[u][d], s);
    rrbkr[u] = s;
  }
  __syncthreads();

  const int tx = tid & 15, ty = tid >> 4;
  float acc[4][4] = {};
  for (int d = 0; d < 64; ++d) {
    float qv[4], kv[4];
#pragma unroll
    for (int r = 0; r < 4; ++r) qv[r] = q_s[ty + 16 * r][d];
#pragma unroll
    for (int c = 0; c < 4; ++c) kv[c] = k_s[tx + 16 * c][d];
#pragma unroll
    for (int r = 0; r < 4; ++r)
#pragma unroll
      for (int c = 0; c < 4; ++c) {
        int uloc = (tx + 16 * c) - (ty + 16 * r) + 63;
        acc[r][c] = fmaf(qv[r], kv[c] + kr_s[uloc][d], acc[r][c]);
      }
  }
  const float scale = 0.125f;
#pragma unroll
  for (int r = 0; r < 4; ++r) {
    int i = ty + 16 * r;
    int gi = i0 + i;
    float ef0 = ef[(((size_t)gi * B_ + b) * NH_ + n) * 2 + 0];
    float ef1 = ef[(((size_t)gi * B_ + b) * NH_ + n) * 2 + 1];
    int si = segi[i];
#pragma unroll
    for (int c = 0; c < 4; ++c) {
      int j = tx + 16 * c;
      int gj = j0 + j;
      int uloc = j - i + 63;
      float val = (acc[r][c] + rwbk[j] + rrbkr[uloc] + ((si != segj[j]) ? ef1 : ef0)) * scale;
      if (gj > gi) val = -1e30f;
      out[(size_t)i * S_ + j] = val;
    }
  }
}

// ---------------- row softmax over j (512), in place -------------------
__global__ __launch_bounds__(256) void softmax_k(float* __restrict__ scores) {
  int i = blockIdx.x, bn = blockIdx.y;
  float* row = scores + ((size_t)bn * S_ + i) * S_;
  int tid = threadIdx.x;
  float2 x = *reinterpret_cast<float2*>(&row[tid * 2]);
  __shared__ float red[8];
  float m = fmaxf(x.x, x.y);
#pragma unroll
  for (int off = 32; off >= 1; off >>= 1) m = fmaxf(m, __shfl_xor(m, off));
  if ((tid & 63) == 0) red[tid >> 6] = m;
  __syncthreads();
  float M4 = fmaxf(fmaxf(red[0], red[1]), fmaxf(red[2], red[3]));
  float e0 = expf(x.x - M4), e1 = expf(x.y - M4);
  float s = e0 + e1;
#pragma unroll
  for (int off = 32; off >= 1; off >>= 1) s += __shfl_xor(s, off);
  if ((tid & 63) == 0) red[4 + (tid >> 6)] = s;
  __syncthreads();
  float inv = 1.0f / (red[4] + red[5] + red[6] + red[7]);
  float2 o = make_float2(e0 * inv, e1 * inv);
  *reinterpret_cast<float2*>(&row[tid * 2]) = o;
}

// ---------------- PV: av[i,b,n,:] = sum_j P[bn,i,j] v[j,b,n,:] (causal) -
__global__ __launch_bounds__(256) void pv_k(const float* __restrict__ P,
                                            const float* __restrict__ v,
                                            float* __restrict__ av) {
  const int ib = blockIdx.x, bn = blockIdx.y;
  const int b = bn / NH_, n = bn % NH_;
  const int i0 = ib * 64;
  const int tid = threadIdx.x;
  const int tx = tid & 15, ty = tid >> 4;
  __shared__ float P_s[64][68];
  __shared__ float V_s[64][68];
  float acc[4][4] = {};
  for (int jb = 0; jb <= ib; ++jb) {
    int j0 = jb * 64;
#pragma unroll
    for (int rep = 0; rep < 4; ++rep) {
      int f = tid + rep * 256;
      int row = f >> 4, dq = f & 15;
      *reinterpret_cast<float4*>(&P_s[row][dq * 4]) =
          *reinterpret_cast<const float4*>(&P[((size_t)bn * S_ + i0 + row) * S_ + j0 + dq * 4]);
      *reinterpret_cast<float4*>(&V_s[row][dq * 4]) =
          *reinterpret_cast<const float4*>(&v[((size_t)(j0 + row) * B_ + b) * DM_ + n * DH_ + dq * 4]);
    }
    __syncthreads();
#pragma unroll
    for (int jl = 0; jl < 64; ++jl) {
      float pv[4], vv[4];
#pragma unroll
      for (int r = 0; r < 4; ++r) pv[r] = P_s[ty + 16 * r][jl];
#pragma unroll
      for (int c = 0; c < 4; ++c) vv[c] = V_s[jl][tx + 16 * c];
#pragma unroll
      for (int r = 0; r < 4; ++r)
#pragma unroll
        for (int c = 0; c < 4; ++c) acc[r][c] = fmaf(pv[r], vv[c], acc[r][c]);
    }
    __syncthreads();
  }
#pragma unroll
  for (int r = 0; r < 4; ++r) {
    int i = i0 + ty + 16 * r;
#pragma unroll
    for (int c = 0; c < 4; ++c) {
      int d = tx + 16 * c;
      av[((size_t)i * B_ + b) * DM_ + n * DH_ + d] = acc[r][c];
    }
  }
}

// ---------------- residual + LayerNorm: out = LN(a+b)*g+beta ------------
__global__ __launch_bounds__(256) void add_ln_k(const float* __restrict__ a,
                                                const float* __restrict__ bb,
                                                float* __restrict__ out,
                                                const float* __restrict__ g,
                                                const float* __restrict__ beta) {
  int t = blockIdx.x, tid = threadIdx.x;
  const float* ap = a + (size_t)t * DM_;
  const float* bp = bb + (size_t)t * DM_;
  float x[3];
  float s1 = 0.f, s2 = 0.f;
#pragma unroll
  for (int j = 0; j < 3; ++j) {
    int d = tid + j * 256;
    x[j] = ap[d] + bp[d];
    s1 += x[j];
    s2 += x[j] * x[j];
  }
  __shared__ float r1[4], r2[4];
#pragma unroll
  for (int off = 32; off >= 1; off >>= 1) {
    s1 += __shfl_xor(s1, off);
    s2 += __shfl_xor(s2, off);
  }
  if ((tid & 63) == 0) { r1[tid >> 6] = s1; r2[tid >> 6] = s2; }
  __syncthreads();
  float S1 = r1[0] + r1[1] + r1[2] + r1[3];
  float S2 = r2[0] + r2[1] + r2[2] + r2[3];
  float mu = S1 * (1.0f / 768.0f);
  float var = S2 * (1.0f / 768.0f) - mu * mu;
  float rstd = rsqrtf(var + 1e-5f);
  float* op = out + (size_t)t * DM_;
#pragma unroll
  for (int j = 0; j < 3; ++j) {
    int d = tid + j * 256;
    op[d] = (x[j] - mu) * rstd * g[d] + beta[d];
  }
}

// ---------------- launch ------------------------------------------------
extern "C" void kernel_launch(void* const* d_in, const int* in_sizes, int n_in,
                              void* d_out, int out_size, void* d_ws, size_t ws_size,
                              hipStream_t stream) {
  const int*   inp_k    = (const int*)d_in[0];
  const int*   seg_id   = (const int*)d_in[1];
  const float* emb      = (const float*)d_in[2];
  const float* Wq       = (const float*)d_in[3];
  const float* Wk       = (const float*)d_in[4];
  const float* Wv       = (const float*)d_in[5];
  const float* Wr       = (const float*)d_in[6];
  const float* proj_o   = (const float*)d_in[7];
  const float* r_w_bias = (const float*)d_in[8];
  const float* r_r_bias = (const float*)d_in[9];
  const float* r_s_bias = (const float*)d_in[10];
  const float* seg_emb  = (const float*)d_in[11];
  const float* ln_g     = (const float*)d_in[12];
  const float* ln_b     = (const float*)d_in[13];
  const float* W1       = (const float*)d_in[14];
  const float* b1       = (const float*)d_in[15];
  const float* W2       = (const float*)d_in[16];
  const float* b2       = (const float*)d_in[17];
  const float* smax_b   = (const float*)d_in[18];
  float* out = (float*)d_out;

  float* ws = (float*)d_ws;
  float* h   = ws;                    // 2048*768
  float* q   = h   + (size_t)M_ * DM_;
  float* kx  = q   + (size_t)M_ * DM_;
  float* vx  = kx  + (size_t)M_ * DM_;
  float* av  = vx  + (size_t)M_ * DM_;
  float* ao  = av  + (size_t)M_ * DM_;
  float* krb = ao  + (size_t)M_ * DM_;        // 1024*768
  float* rb  = krb + (size_t)2 * S_ * DM_;    // 1024*768
  float* efb = rb  + (size_t)2 * S_ * DM_;    // 2048*12*2
  float* mid = efb + (size_t)M_ * NH_ * 2;    // 2048*3072
  float* sc  = mid + (size_t)M_ * DI_;        // 48*512*512

  gather_k<<<M_, 256, 0, stream>>>(inp_k, emb, h);
  posemb_k<<<2 * S_, 256, 0, stream>>>(rb);
  gemm_k<false, 0><<<dim3(DM_ / 128, (2 * S_) / 128), 256, 0, stream>>>(rb, Wr, nullptr, krb, 2 * S_, DM_, DM_);

  for (int l = 0; l < 4; ++l) {
    gemm_k<false, 0><<<dim3(DM_ / 128, M_ / 128), 256, 0, stream>>>(h, Wq, nullptr, q, M_, DM_, DM_);
    gemm_k<false, 0><<<dim3(DM_ / 128, M_ / 128), 256, 0, stream>>>(h, Wk, nullptr, kx, M_, DM_, DM_);
    gemm_k<false, 0><<<dim3(DM_ / 128, M_ / 128), 256, 0, stream>>>(h, Wv, nullptr, vx, M_, DM_, DM_);
    ef_k<<<(M_ * NH_ * 2) / 256, 256, 0, stream>>>(q, r_s_bias, seg_emb, efb, l);
    score_k<<<dim3(8, 8, B_ * NH_), 256, 0, stream>>>(q, kx, krb, efb, seg_id, r_w_bias, r_r_bias, sc, l);
    softmax_k<<<dim3(S_, B_ * NH_), 256, 0, stream>>>(sc);
    pv_k<<<dim3(8, B_ * NH_), 256, 0, stream>>>(sc, vx, av);
    gemm_k<true, 0><<<dim3(DM_ / 128, M_ / 128), 256, 0, stream>>>(av, proj_o, nullptr, ao, M_, DM_, DM_);
    add_ln_k<<<M_, 256, 0, stream>>>(ao, h, h, ln_g, ln_b);
    gemm_k<false, 2><<<dim3(DI_ / 128, M_ / 128), 256, 0, stream>>>(h, W1, b1, mid, M_, DI_, DM_);
    gemm_k<false, 1><<<dim3(DM_ / 128, M_ / 128), 256, 0, stream>>>(mid, W2, b2, ao, M_, DM_, DI_);
    add_ln_k<<<M_, 256, 0, stream>>>(ao, h, h, ln_g, ln_b);
  }
  gemm_k<true, 1><<<dim3(V_ / 128, M_ / 128), 256, 0, stream>>>(h, emb, smax_b, out, M_, V_, DM_);
}

// Round 2
// 2359.989 us; speedup vs baseline: 2.4003x; 2.4003x over previous
//
#include <hip/hip_runtime.h>
#include <hip/hip_bf16.h>

typedef unsigned short u16;
typedef __attribute__((ext_vector_type(8))) short s16x8;
typedef __attribute__((ext_vector_type(4))) float f32x4;

// ---------------- constants ----------------
constexpr int S_   = 512;
constexpr int B_   = 4;
constexpr int NH_  = 12;
constexpr int DH_  = 64;
constexpr int DM_  = 768;
constexpr int DI_  = 3072;
constexpr int V_   = 32000;
constexpr int M_   = S_ * B_;   // 2048 tokens

// ---------------- bf16 helpers ----------------
__device__ __forceinline__ u16 bf16_rne(float x) {
  unsigned u = __float_as_uint(x);
  u += 0x7FFFu + ((u >> 16) & 1u);
  return (u16)(u >> 16);
}
__device__ __forceinline__ float bf16_f(u16 h) { return __uint_as_float(((unsigned)h) << 16); }
__device__ __forceinline__ void bf16_split(float x, u16& h, u16& l) {
  h = bf16_rne(x);
  l = bf16_rne(x - bf16_f(h));
}

__device__ __forceinline__ void gl_lds16(const void* g, void* l) {
  __builtin_amdgcn_global_load_lds(
      (const __attribute__((address_space(1))) unsigned int*)g,
      (__attribute__((address_space(3))) unsigned int*)l, 16, 0, 0);
}

// ---------------- MFMA GEMM: C[M,N] = (Ahi+Alo)[M,K] . (Bhi+Blo)[N,K]^T --
// NT=3: split products hi*hi + hi*lo + lo*hi.  NT=1: hi*hi only.
// EPI: 0 -> C fp32 ; 1 -> C fp32 + bias ; 2 -> bias + relu -> Chi/Clo bf16
// grid = (M/128, N/128)  (m-major so concurrent blocks share B tiles in L2)
template<int NT, int EPI>
__global__ __launch_bounds__(256) void mgemm_k(
    const u16* __restrict__ Ahi, const u16* __restrict__ Alo,
    const u16* __restrict__ Bhi, const u16* __restrict__ Blo,
    const float* __restrict__ bias, float* __restrict__ C,
    u16* __restrict__ Chi, u16* __restrict__ Clo,
    int M, int N, int K) {
  constexpr int NB = (NT == 3) ? 2 : 1;
  __shared__ u16 As[NB][128][32];
  __shared__ u16 Bs[NB][128][32];
  const int tid = threadIdx.x;
  const int wid = tid >> 6, lane = tid & 63;
  const int m0 = blockIdx.x * 128, n0 = blockIdx.y * 128;
  const int lrow = lane >> 2, lcolb = (lane & 3) * 8;
  const int wr = wid >> 1, wc = wid & 1;
  const int fr = lane & 15, fk = lane >> 4;

  f32x4 acc[4][4];
#pragma unroll
  for (int i = 0; i < 4; ++i)
#pragma unroll
    for (int j = 0; j < 4; ++j)
#pragma unroll
      for (int r = 0; r < 4; ++r) acc[i][j][r] = 0.f;

  for (int k0 = 0; k0 < K; k0 += 32) {
    if (NT == 3) {
      const u16* src = (wid == 0) ? Ahi : (wid == 1) ? Alo : (wid == 2) ? Bhi : Blo;
      const int rbase = (wid < 2) ? m0 : n0;
      u16* dst = (wid == 0) ? &As[0][0][0] : (wid == 1) ? &As[NB - 1][0][0]
               : (wid == 2) ? &Bs[0][0][0] : &Bs[NB - 1][0][0];
#pragma unroll
      for (int i = 0; i < 8; ++i)
        gl_lds16(src + (size_t)(rbase + i * 16 + lrow) * K + k0 + lcolb, dst + (i * 16) * 32);
    } else {
      const u16* src = (wid < 2) ? Ahi : Bhi;
      const int rbase = ((wid < 2) ? m0 : n0) + (wid & 1) * 64;
      u16* dst = ((wid < 2) ? &As[0][0][0] : &Bs[0][0][0]) + (wid & 1) * 64 * 32;
#pragma unroll
      for (int i = 0; i < 4; ++i)
        gl_lds16(src + (size_t)(rbase + i * 16 + lrow) * K + k0 + lcolb, dst + (i * 16) * 32);
    }
    __syncthreads();

    s16x8 a0[4], a1[4];
#pragma unroll
    for (int fi = 0; fi < 4; ++fi) {
      a0[fi] = *(const s16x8*)&As[0][wr * 64 + fi * 16 + fr][fk * 8];
      if (NT == 3) a1[fi] = *(const s16x8*)&As[NB - 1][wr * 64 + fi * 16 + fr][fk * 8];
    }
#pragma unroll
    for (int fj = 0; fj < 4; ++fj) {
      s16x8 b0 = *(const s16x8*)&Bs[0][wc * 64 + fj * 16 + fr][fk * 8];
      s16x8 b1 = b0;
      if (NT == 3) b1 = *(const s16x8*)&Bs[NB - 1][wc * 64 + fj * 16 + fr][fk * 8];
#pragma unroll
      for (int fi = 0; fi < 4; ++fi) {
        acc[fi][fj] = __builtin_amdgcn_mfma_f32_16x16x32_bf16(a0[fi], b0, acc[fi][fj], 0, 0, 0);
        if (NT == 3) {
          acc[fi][fj] = __builtin_amdgcn_mfma_f32_16x16x32_bf16(a0[fi], b1, acc[fi][fj], 0, 0, 0);
          acc[fi][fj] = __builtin_amdgcn_mfma_f32_16x16x32_bf16(a1[fi], b0, acc[fi][fj], 0, 0, 0);
        }
      }
    }
    __syncthreads();
  }

#pragma unroll
  for (int fi = 0; fi < 4; ++fi)
#pragma unroll
    for (int fj = 0; fj < 4; ++fj)
#pragma unroll
      for (int r = 0; r < 4; ++r) {
        int m = m0 + wr * 64 + fi * 16 + fk * 4 + r;
        int n = n0 + wc * 64 + fj * 16 + fr;
        float y = acc[fi][fj][r];
        if (EPI >= 1) y += bias[n];
        if (EPI == 2) {
          y = fmaxf(y, 0.f);
          u16 hh, ll;
          bf16_split(y, hh, ll);
          Chi[(size_t)m * N + n] = hh;
          Clo[(size_t)m * N + n] = ll;
        } else {
          C[(size_t)m * N + n] = y;
        }
      }
}

// ---------------- fp32 tiled GEMM (used once for kr = r . Wr) ------------
template<bool TB, int EPI>
__global__ __launch_bounds__(256) void gemm_k(const float* __restrict__ A,
                                              const float* __restrict__ Bm,
                                              const float* __restrict__ bias,
                                              float* __restrict__ C,
                                              int M, int N, int K) {
  __shared__ float As[16][128 + 4];
  __shared__ float Bs[16][128 + 4];
  const int tid = threadIdx.x;
  const int tx = tid & 15;
  const int ty = tid >> 4;
  const int m0 = blockIdx.y * 128;
  const int n0 = blockIdx.x * 128;

  float acc[8][8];
#pragma unroll
  for (int i = 0; i < 8; ++i)
#pragma unroll
    for (int j = 0; j < 8; ++j) acc[i][j] = 0.f;

  for (int k0 = 0; k0 < K; k0 += 16) {
#pragma unroll
    for (int rep = 0; rep < 2; ++rep) {
      int f = tid + rep * 256;
      int row = f >> 2, kq = f & 3;
      float4 av = *reinterpret_cast<const float4*>(&A[(size_t)(m0 + row) * K + k0 + kq * 4]);
      As[kq * 4 + 0][row] = av.x;
      As[kq * 4 + 1][row] = av.y;
      As[kq * 4 + 2][row] = av.z;
      As[kq * 4 + 3][row] = av.w;
    }
    if (!TB) {
#pragma unroll
      for (int rep = 0; rep < 2; ++rep) {
        int f = tid + rep * 256;
        int row = f >> 5, nq = f & 31;
        float4 bv = *reinterpret_cast<const float4*>(&Bm[(size_t)(k0 + row) * N + n0 + nq * 4]);
        *reinterpret_cast<float4*>(&Bs[row][nq * 4]) = bv;
      }
    } else {
#pragma unroll
      for (int rep = 0; rep < 2; ++rep) {
        int f = tid + rep * 256;
        int nr = f >> 2, kq = f & 3;
        float4 bv = *reinterpret_cast<const float4*>(&Bm[(size_t)(n0 + nr) * K + k0 + kq * 4]);
        Bs[kq * 4 + 0][nr] = bv.x;
        Bs[kq * 4 + 1][nr] = bv.y;
        Bs[kq * 4 + 2][nr] = bv.z;
        Bs[kq * 4 + 3][nr] = bv.w;
      }
    }
    __syncthreads();
#pragma unroll
    for (int kk = 0; kk < 16; ++kk) {
      float a[8], b[8];
#pragma unroll
      for (int j = 0; j < 4; ++j) { a[j] = As[kk][ty * 4 + j]; a[4 + j] = As[kk][ty * 4 + 64 + j]; }
#pragma unroll
      for (int j = 0; j < 4; ++j) { b[j] = Bs[kk][tx * 4 + j]; b[4 + j] = Bs[kk][tx * 4 + 64 + j]; }
#pragma unroll
      for (int i = 0; i < 8; ++i)
#pragma unroll
        for (int j = 0; j < 8; ++j) acc[i][j] = fmaf(a[i], b[j], acc[i][j]);
    }
    __syncthreads();
  }
#pragma unroll
  for (int i = 0; i < 8; ++i) {
    int m = m0 + ty * 4 + (i < 4 ? i : 64 + i - 4);
#pragma unroll
    for (int jh = 0; jh < 2; ++jh) {
      int nb = n0 + tx * 4 + jh * 64;
      float4 v;
      float* vp = &v.x;
#pragma unroll
      for (int j = 0; j < 4; ++j) {
        float x = acc[i][jh * 4 + j];
        if (EPI >= 1) x += bias[nb + j];
        if (EPI == 2) x = fmaxf(x, 0.f);
        vp[j] = x;
      }
      *reinterpret_cast<float4*>(&C[(size_t)m * N + nb]) = v;
    }
  }
}

// ---------------- weight prep: transpose + split cast --------------------
// W: [K][N] fp32 -> hi/lo: [N][K] bf16
__global__ __launch_bounds__(256) void tsplit_k(const float* __restrict__ W,
                                                u16* __restrict__ hi, u16* __restrict__ lo,
                                                int K, int N) {
  __shared__ float t[32][33];
  int kb = blockIdx.x * 32, nb = blockIdx.y * 32;
  int tx = threadIdx.x & 31, ty = threadIdx.x >> 5;  // ty: 0..7
#pragma unroll
  for (int r = 0; r < 32; r += 8)
    t[ty + r][tx] = W[(size_t)(kb + ty + r) * N + nb + tx];
  __syncthreads();
#pragma unroll
  for (int r = 0; r < 32; r += 8) {
    float x = t[tx][ty + r];
    u16 h, l;
    bf16_split(x, h, l);
    size_t o = (size_t)(nb + ty + r) * K + kb + tx;
    hi[o] = h;
    lo[o] = l;
  }
}

// elementwise split (already [N][K] layout)
__global__ __launch_bounds__(256) void psplit_k(const float* __restrict__ W,
                                                u16* __restrict__ hi, u16* __restrict__ lo, int n) {
  int id = blockIdx.x * 256 + threadIdx.x;
  if (id >= n) return;
  u16 h, l;
  bf16_split(W[id], h, l);
  hi[id] = h;
  lo[id] = l;
}

// hi-only cast, 4 elems/thread
__global__ __launch_bounds__(256) void cast4_k(const float* __restrict__ x, u16* __restrict__ hi, int n4) {
  int id = blockIdx.x * 256 + threadIdx.x;
  if (id >= n4) return;
  float4 v = *reinterpret_cast<const float4*>(&x[id * 4]);
  hi[id * 4 + 0] = bf16_rne(v.x);
  hi[id * 4 + 1] = bf16_rne(v.y);
  hi[id * 4 + 2] = bf16_rne(v.z);
  hi[id * 4 + 3] = bf16_rne(v.w);
}

// ---------------- embedding gather + split ------------------------------
__global__ __launch_bounds__(256) void gather_k(const int* __restrict__ idx,
                                                const float* __restrict__ emb,
                                                float* __restrict__ h,
                                                u16* __restrict__ hh, u16* __restrict__ hl) {
  int t = blockIdx.x, tid = threadIdx.x;
  int row = idx[t];
  if (tid < 192) {
    float4 v = *reinterpret_cast<const float4*>(&emb[(size_t)row * DM_ + tid * 4]);
    *reinterpret_cast<float4*>(&h[(size_t)t * DM_ + tid * 4]) = v;
    const float* vp = &v.x;
#pragma unroll
    for (int c = 0; c < 4; ++c) {
      u16 a, b;
      bf16_split(vp[c], a, b);
      hh[(size_t)t * DM_ + tid * 4 + c] = a;
      hl[(size_t)t * DM_ + tid * 4 + c] = b;
    }
  }
}

// ---------------- positional embedding ----------------------------------
__global__ __launch_bounds__(256) void posemb_k(float* __restrict__ r) {
  int u = blockIdx.x, tid = threadIdx.x;
  float pos = (float)(S_ - u);
  for (int d = tid; d < DM_; d += 256) {
    int kidx = d < 384 ? d : d - 384;
    float invf = expf(-(float)kidx * (9.210340371976184f / 384.0f));
    float arg = pos * invf;
    r[(size_t)u * DM_ + d] = (d < 384) ? sinf(arg) : cosf(arg);
  }
}

// ---------------- ef ----------------------------------------------------
__global__ __launch_bounds__(256) void ef_k(const float* __restrict__ q,
                                            const float* __restrict__ rsb,
                                            const float* __restrict__ segemb,
                                            float* __restrict__ ef, int layer) {
  int id = blockIdx.x * 256 + threadIdx.x;
  int t = id / 24, rem = id % 24, n = rem >> 1, s = rem & 1;
  const float* qp = q + (size_t)t * DM_ + n * DH_;
  const float* rp = rsb + ((size_t)layer * NH_ + n) * DH_;
  const float* sp = segemb + (((size_t)layer * 2 + s) * NH_ + n) * DH_;
  float acc = 0.f;
#pragma unroll
  for (int d = 0; d < DH_; ++d) acc = fmaf(qp[d] + rp[d], sp[d], acc);
  ef[id] = acc;
}

// ---------------- fused attention scores --------------------------------
__global__ __launch_bounds__(256) void score_k(const float* __restrict__ q,
                                               const float* __restrict__ kb,
                                               const float* __restrict__ kr,
                                               const float* __restrict__ ef,
                                               const int* __restrict__ seg,
                                               const float* __restrict__ rwb_all,
                                               const float* __restrict__ rrb_all,
                                               float* __restrict__ scores, int layer) {
  const int jb = blockIdx.x, ib = blockIdx.y, bn = blockIdx.z;
  const int b = bn / NH_, n = bn % NH_;
  const int i0 = ib * 64, j0 = jb * 64;
  const int tid = threadIdx.x;
  float* out = scores + ((size_t)bn * S_ + i0) * S_ + j0;

  if (j0 > i0 + 63) {
    float4 neg = make_float4(-1e30f, -1e30f, -1e30f, -1e30f);
#pragma unroll
    for (int rep = 0; rep < 4; ++rep) {
      int f = tid + rep * 256;
      int row = f >> 4, c4 = f & 15;
      *reinterpret_cast<float4*>(&out[(size_t)row * S_ + c4 * 4]) = neg;
    }
    return;
  }

  __shared__ float q_s[64][68];
  __shared__ float k_s[64][68];
  __shared__ float kr_s[128][68];
  __shared__ float rwb_s[64], rrb_s[64];
  __shared__ float rwbk[64], rrbkr[128];
  __shared__ int segi[64], segj[64];

#pragma unroll
  for (int rep = 0; rep < 4; ++rep) {
    int f = tid + rep * 256;
    int row = f >> 4, dq = f & 15;
    float4 qv = *reinterpret_cast<const float4*>(&q[((size_t)(i0 + row) * B_ + b) * DM_ + n * DH_ + dq * 4]);
    *reinterpret_cast<float4*>(&q_s[row][dq * 4]) = qv;
    float4 kv = *reinterpret_cast<const float4*>(&kb[((size_t)(j0 + row) * B_ + b) * DM_ + n * DH_ + dq * 4]);
    *reinterpret_cast<float4*>(&k_s[row][dq * 4]) = kv;
  }
  int ubase = S_ + j0 - i0 - 63;
#pragma unroll
  for (int rep = 0; rep < 8; ++rep) {
    int f = tid + rep * 256;
    int row = f >> 4, dq = f & 15;
    int ur = ubase + row; ur = ur > 2 * S_ - 1 ? 2 * S_ - 1 : ur;
    float4 v = *reinterpret_cast<const float4*>(&kr[(size_t)ur * DM_ + n * DH_ + dq * 4]);
    *reinterpret_cast<float4*>(&kr_s[row][dq * 4]) = v;
  }
  if (tid < 64)       rwb_s[tid]      = rwb_all[((size_t)layer * NH_ + n) * DH_ + tid];
  else if (tid < 128) rrb_s[tid - 64] = rrb_all[((size_t)layer * NH_ + n) * DH_ + (tid - 64)];
  else if (tid < 192) segi[tid - 128] = seg[(i0 + tid - 128) * B_ + b];
  else                segj[tid - 192] = seg[(j0 + tid - 192) * B_ + b];
  __syncthreads();

  if (tid < 64) {
    float s = 0.f;
#pragma unroll
    for (int d = 0; d < 64; ++d) s = fmaf(rwb_s[d], k_s[tid][d], s);
    rwbk[tid] = s;
  } else if (tid < 192) {
    int u = tid - 64;
    float s = 0.f;
#pragma unroll
    for (int d = 0; d < 64; ++d) s = fmaf(rrb_s[d], kr_s[u][d], s);
    rrbkr[u] = s;
  }
  __syncthreads();

  const int tx = tid & 15, ty = tid >> 4;
  float acc[4][4] = {};
  for (int d = 0; d < 64; ++d) {
    float qv[4], kv[4];
#pragma unroll
    for (int r = 0; r < 4; ++r) qv[r] = q_s[ty + 16 * r][d];
#pragma unroll
    for (int c = 0; c < 4; ++c) kv[c] = k_s[tx + 16 * c][d];
#pragma unroll
    for (int r = 0; r < 4; ++r)
#pragma unroll
      for (int c = 0; c < 4; ++c) {
        int uloc = (tx + 16 * c) - (ty + 16 * r) + 63;
        acc[r][c] = fmaf(qv[r], kv[c] + kr_s[uloc][d], acc[r][c]);
      }
  }
  const float scale = 0.125f;
#pragma unroll
  for (int r = 0; r < 4; ++r) {
    int i = ty + 16 * r;
    int gi = i0 + i;
    float ef0 = ef[(((size_t)gi * B_ + b) * NH_ + n) * 2 + 0];
    float ef1 = ef[(((size_t)gi * B_ + b) * NH_ + n) * 2 + 1];
    int si = segi[i];
#pragma unroll
    for (int c = 0; c < 4; ++c) {
      int j = tx + 16 * c;
      int gj = j0 + j;
      int uloc = j - i + 63;
      float val = (acc[r][c] + rwbk[j] + rrbkr[uloc] + ((si != segj[j]) ? ef1 : ef0)) * scale;
      if (gj > gi) val = -1e30f;
      out[(size_t)i * S_ + j] = val;
    }
  }
}

// ---------------- softmax ----------------------------------------------
__global__ __launch_bounds__(256) void softmax_k(float* __restrict__ scores) {
  int i = blockIdx.x, bn = blockIdx.y;
  float* row = scores + ((size_t)bn * S_ + i) * S_;
  int tid = threadIdx.x;
  float2 x = *reinterpret_cast<float2*>(&row[tid * 2]);
  __shared__ float red[8];
  float m = fmaxf(x.x, x.y);
#pragma unroll
  for (int off = 32; off >= 1; off >>= 1) m = fmaxf(m, __shfl_xor(m, off));
  if ((tid & 63) == 0) red[tid >> 6] = m;
  __syncthreads();
  float M4 = fmaxf(fmaxf(red[0], red[1]), fmaxf(red[2], red[3]));
  float e0 = expf(x.x - M4), e1 = expf(x.y - M4);
  float s = e0 + e1;
#pragma unroll
  for (int off = 32; off >= 1; off >>= 1) s += __shfl_xor(s, off);
  if ((tid & 63) == 0) red[4 + (tid >> 6)] = s;
  __syncthreads();
  float inv = 1.0f / (red[4] + red[5] + red[6] + red[7]);
  float2 o = make_float2(e0 * inv, e1 * inv);
  *reinterpret_cast<float2*>(&row[tid * 2]) = o;
}

// ---------------- PV (writes av as bf16 hi/lo) ---------------------------
__global__ __launch_bounds__(256) void pv_k(const float* __restrict__ P,
                                            const float* __restrict__ v,
                                            u16* __restrict__ avh, u16* __restrict__ avl) {
  const int ib = blockIdx.x, bn = blockIdx.y;
  const int b = bn / NH_, n = bn % NH_;
  const int i0 = ib * 64;
  const int tid = threadIdx.x;
  const int tx = tid & 15, ty = tid >> 4;
  __shared__ float P_s[64][68];
  __shared__ float V_s[64][68];
  float acc[4][4] = {};
  for (int jb = 0; jb <= ib; ++jb) {
    int j0 = jb * 64;
#pragma unroll
    for (int rep = 0; rep < 4; ++rep) {
      int f = tid + rep * 256;
      int row = f >> 4, dq = f & 15;
      *reinterpret_cast<float4*>(&P_s[row][dq * 4]) =
          *reinterpret_cast<const float4*>(&P[((size_t)bn * S_ + i0 + row) * S_ + j0 + dq * 4]);
      *reinterpret_cast<float4*>(&V_s[row][dq * 4]) =
          *reinterpret_cast<const float4*>(&v[((size_t)(j0 + row) * B_ + b) * DM_ + n * DH_ + dq * 4]);
    }
    __syncthreads();
#pragma unroll
    for (int jl = 0; jl < 64; ++jl) {
      float pv[4], vv[4];
#pragma unroll
      for (int r = 0; r < 4; ++r) pv[r] = P_s[ty + 16 * r][jl];
#pragma unroll
      for (int c = 0; c < 4; ++c) vv[c] = V_s[jl][tx + 16 * c];
#pragma unroll
      for (int r = 0; r < 4; ++r)
#pragma unroll
        for (int c = 0; c < 4; ++c) acc[r][c] = fmaf(pv[r], vv[c], acc[r][c]);
    }
    __syncthreads();
  }
#pragma unroll
  for (int r = 0; r < 4; ++r) {
    int i = i0 + ty + 16 * r;
#pragma unroll
    for (int c = 0; c < 4; ++c) {
      int d = tx + 16 * c;
      u16 a, bb;
      bf16_split(acc[r][c], a, bb);
      size_t o = ((size_t)i * B_ + b) * DM_ + n * DH_ + d;
      avh[o] = a;
      avl[o] = bb;
    }
  }
}

// ---------------- residual + LayerNorm (+ bf16 hi/lo copy) ---------------
__global__ __launch_bounds__(256) void add_ln_k(const float* __restrict__ a,
                                                const float* __restrict__ bb,
                                                float* __restrict__ out,
                                                u16* __restrict__ oh, u16* __restrict__ ol,
                                                const float* __restrict__ g,
                                                const float* __restrict__ beta) {
  int t = blockIdx.x, tid = threadIdx.x;
  const float* ap = a + (size_t)t * DM_;
  const float* bp = bb + (size_t)t * DM_;
  float x[3];
  float s1 = 0.f, s2 = 0.f;
#pragma unroll
  for (int j = 0; j < 3; ++j) {
    int d = tid + j * 256;
    x[j] = ap[d] + bp[d];
    s1 += x[j];
    s2 += x[j] * x[j];
  }
  __shared__ float r1[4], r2[4];
#pragma unroll
  for (int off = 32; off >= 1; off >>= 1) {
    s1 += __shfl_xor(s1, off);
    s2 += __shfl_xor(s2, off);
  }
  if ((tid & 63) == 0) { r1[tid >> 6] = s1; r2[tid >> 6] = s2; }
  __syncthreads();
  float S1 = r1[0] + r1[1] + r1[2] + r1[3];
  float S2 = r2[0] + r2[1] + r2[2] + r2[3];
  float mu = S1 * (1.0f / 768.0f);
  float var = S2 * (1.0f / 768.0f) - mu * mu;
  float rstd = rsqrtf(var + 1e-5f);
  float* op = out + (size_t)t * DM_;
#pragma unroll
  for (int j = 0; j < 3; ++j) {
    int d = tid + j * 256;
    float y = (x[j] - mu) * rstd * g[d] + beta[d];
    op[d] = y;
    u16 h, l;
    bf16_split(y, h, l);
    oh[(size_t)t * DM_ + d] = h;
    ol[(size_t)t * DM_ + d] = l;
  }
}

// ---------------- launch ------------------------------------------------
extern "C" void kernel_launch(void* const* d_in, const int* in_sizes, int n_in,
                              void* d_out, int out_size, void* d_ws, size_t ws_size,
                              hipStream_t stream) {
  const int*   inp_k    = (const int*)d_in[0];
  const int*   seg_id   = (const int*)d_in[1];
  const float* emb      = (const float*)d_in[2];
  const float* Wq       = (const float*)d_in[3];
  const float* Wk       = (const float*)d_in[4];
  const float* Wv       = (const float*)d_in[5];
  const float* Wr       = (const float*)d_in[6];
  const float* proj_o   = (const float*)d_in[7];
  const float* r_w_bias = (const float*)d_in[8];
  const float* r_r_bias = (const float*)d_in[9];
  const float* r_s_bias = (const float*)d_in[10];
  const float* seg_emb  = (const float*)d_in[11];
  const float* ln_g     = (const float*)d_in[12];
  const float* ln_b     = (const float*)d_in[13];
  const float* W1       = (const float*)d_in[14];
  const float* b1       = (const float*)d_in[15];
  const float* W2       = (const float*)d_in[16];
  const float* b2       = (const float*)d_in[17];
  const float* smax_b   = (const float*)d_in[18];
  float* out = (float*)d_out;

  float* ws = (float*)d_ws;
  float* h   = ws;                                 // 2048*768
  float* q   = h   + (size_t)M_ * DM_;
  float* kx  = q   + (size_t)M_ * DM_;
  float* vx  = kx  + (size_t)M_ * DM_;
  float* ao  = vx  + (size_t)M_ * DM_;
  float* krb = ao  + (size_t)M_ * DM_;             // 1024*768
  float* rb  = krb + (size_t)2 * S_ * DM_;         // 1024*768
  float* efb = rb  + (size_t)2 * S_ * DM_;         // 2048*24
  float* sc  = efb + (size_t)M_ * NH_ * 2;         // 48*512*512
  u16* embh  = (u16*)sc;                           // alias (used after layers)
  u16* p     = (u16*)(sc + (size_t)B_ * NH_ * S_ * S_);
  u16* hh    = p;  p += (size_t)M_ * DM_;
  u16* hl    = p;  p += (size_t)M_ * DM_;
  u16* avh   = p;  p += (size_t)M_ * DM_;
  u16* avl   = p;  p += (size_t)M_ * DM_;
  u16* midh  = p;  p += (size_t)M_ * DI_;
  u16* midl  = p;  p += (size_t)M_ * DI_;
  u16* wqh   = p;  p += (size_t)DM_ * DM_;
  u16* wql   = p;  p += (size_t)DM_ * DM_;
  u16* wkh   = p;  p += (size_t)DM_ * DM_;
  u16* wkl   = p;  p += (size_t)DM_ * DM_;
  u16* wvh   = p;  p += (size_t)DM_ * DM_;
  u16* wvl   = p;  p += (size_t)DM_ * DM_;
  u16* w1h   = p;  p += (size_t)DM_ * DI_;
  u16* w1l   = p;  p += (size_t)DM_ * DI_;
  u16* w2h   = p;  p += (size_t)DM_ * DI_;
  u16* w2l   = p;  p += (size_t)DM_ * DI_;
  u16* poh   = p;  p += (size_t)DM_ * DM_;
  u16* pol   = p;  p += (size_t)DM_ * DM_;

  // ---- prep: gather, pos-emb, kr GEMM, weight casts ----
  gather_k<<<M_, 256, 0, stream>>>(inp_k, emb, h, hh, hl);
  posemb_k<<<2 * S_, 256, 0, stream>>>(rb);
  gemm_k<false, 0><<<dim3(DM_ / 128, (2 * S_) / 128), 256, 0, stream>>>(rb, Wr, nullptr, krb, 2 * S_, DM_, DM_);
  tsplit_k<<<dim3(DM_ / 32, DM_ / 32), 256, 0, stream>>>(Wq, wqh, wql, DM_, DM_);
  tsplit_k<<<dim3(DM_ / 32, DM_ / 32), 256, 0, stream>>>(Wk, wkh, wkl, DM_, DM_);
  tsplit_k<<<dim3(DM_ / 32, DM_ / 32), 256, 0, stream>>>(Wv, wvh, wvl, DM_, DM_);
  tsplit_k<<<dim3(DM_ / 32, DI_ / 32), 256, 0, stream>>>(W1, w1h, w1l, DM_, DI_);
  tsplit_k<<<dim3(DI_ / 32, DM_ / 32), 256, 0, stream>>>(W2, w2h, w2l, DI_, DM_);
  psplit_k<<<(DM_ * DM_) / 256, 256, 0, stream>>>(proj_o, poh, pol, DM_ * DM_);

  for (int l = 0; l < 4; ++l) {
    mgemm_k<3, 0><<<dim3(M_ / 128, DM_ / 128), 256, 0, stream>>>(hh, hl, wqh, wql, nullptr, q, nullptr, nullptr, M_, DM_, DM_);
    mgemm_k<3, 0><<<dim3(M_ / 128, DM_ / 128), 256, 0, stream>>>(hh, hl, wkh, wkl, nullptr, kx, nullptr, nullptr, M_, DM_, DM_);
    mgemm_k<3, 0><<<dim3(M_ / 128, DM_ / 128), 256, 0, stream>>>(hh, hl, wvh, wvl, nullptr, vx, nullptr, nullptr, M_, DM_, DM_);
    ef_k<<<(M_ * NH_ * 2) / 256, 256, 0, stream>>>(q, r_s_bias, seg_emb, efb, l);
    score_k<<<dim3(8, 8, B_ * NH_), 256, 0, stream>>>(q, kx, krb, efb, seg_id, r_w_bias, r_r_bias, sc, l);
    softmax_k<<<dim3(S_, B_ * NH_), 256, 0, stream>>>(sc);
    pv_k<<<dim3(8, B_ * NH_), 256, 0, stream>>>(sc, vx, avh, avl);
    mgemm_k<3, 0><<<dim3(M_ / 128, DM_ / 128), 256, 0, stream>>>(avh, avl, poh, pol, nullptr, ao, nullptr, nullptr, M_, DM_, DM_);
    add_ln_k<<<M_, 256, 0, stream>>>(ao, h, h, hh, hl, ln_g, ln_b);
    mgemm_k<3, 2><<<dim3(M_ / 128, DI_ / 128), 256, 0, stream>>>(hh, hl, w1h, w1l, b1, nullptr, midh, midl, M_, DI_, DM_);
    mgemm_k<3, 1><<<dim3(M_ / 128, DM_ / 128), 256, 0, stream>>>(midh, midl, w2h, w2l, b2, ao, nullptr, nullptr, M_, DM_, DI_);
    add_ln_k<<<M_, 256, 0, stream>>>(ao, h, h, hh, hl, ln_g, ln_b);
  }

  // ---- logits: cast emb to bf16 (into sc alias, now dead), plain-bf16 GEMM
  cast4_k<<<(V_ * DM_ / 4 + 255) / 256, 256, 0, stream>>>(emb, embh, V_ * DM_ / 4);
  mgemm_k<1, 1><<<dim3(M_ / 128, V_ / 128), 256, 0, stream>>>(hh, nullptr, embh, nullptr, smax_b, out, nullptr, nullptr, M_, V_, DM_);
}

// Round 3
// 1580.113 us; speedup vs baseline: 3.5850x; 1.4936x over previous
//
#include <hip/hip_runtime.h>
#include <hip/hip_bf16.h>

typedef unsigned short u16;
typedef _Float16 f16;
typedef __attribute__((ext_vector_type(8))) _Float16 f16x8;
typedef __attribute__((ext_vector_type(4))) float f32x4;

// ---------------- constants ----------------
constexpr int S_   = 512;
constexpr int B_   = 4;
constexpr int NH_  = 12;
constexpr int DH_  = 64;
constexpr int DM_  = 768;
constexpr int DI_  = 3072;
constexpr int V_   = 32000;
constexpr int M_   = S_ * B_;   // 2048 tokens

// ---------------- fp16 helpers ----------------
__device__ __forceinline__ float h2f(u16 u) { f16 h; __builtin_memcpy(&h, &u, 2); return (float)h; }
__device__ __forceinline__ u16 f2h(float f) { f16 h = (f16)f; u16 u; __builtin_memcpy(&u, &h, 2); return u; }

__device__ __forceinline__ void gl_lds16(const void* g, void* l) {
  __builtin_amdgcn_global_load_lds(
      (const __attribute__((address_space(1))) unsigned int*)g,
      (__attribute__((address_space(3))) unsigned int*)l, 16, 0, 0);
}

// ---------------- fp16 MFMA GEMM: C[M,N] = A[M,K] . B[N,K]^T ------------
// EPI: 0 -> C fp32 ; 1 -> C fp32 + bias ; 2 -> bias+relu -> Ch fp16 ;
//      4 -> Ch fp16 only
// grid (M/128, N/128); XCD-chunked swizzle (requires nwg % 8 == 0).
template<int EPI>
__global__ __launch_bounds__(256) void mg16_k(
    const u16* __restrict__ A, const u16* __restrict__ Bm,
    const float* __restrict__ bias, float* __restrict__ C,
    u16* __restrict__ Ch, int M, int N, int K) {
  __shared__ u16 As[128][32];
  __shared__ u16 Bs[128][32];
  const int tid = threadIdx.x;
  const int wid = tid >> 6, lane = tid & 63;
  // XCD-aware swizzle: consecutive logical ids (m-fastest) stay on one XCD.
  const int gx = gridDim.x;
  const int nwg = gx * gridDim.y;
  const int id = blockIdx.y * gx + blockIdx.x;
  const int cpx = nwg >> 3;
  const int logical = (id & 7) * cpx + (id >> 3);
  const int m0 = (logical % gx) * 128, n0 = (logical / gx) * 128;
  const int lrow = lane >> 2, lcolb = (lane & 3) * 8;
  const int wr = wid >> 1, wc = wid & 1;
  const int fr = lane & 15, fk = lane >> 4;

  f32x4 acc[4][4];
#pragma unroll
  for (int i = 0; i < 4; ++i)
#pragma unroll
    for (int j = 0; j < 4; ++j)
#pragma unroll
      for (int r = 0; r < 4; ++r) acc[i][j][r] = 0.f;

  for (int k0 = 0; k0 < K; k0 += 32) {
    const u16* src = (wid < 2) ? A : Bm;
    const int rbase = ((wid < 2) ? m0 : n0) + (wid & 1) * 64;
    u16* dst = ((wid < 2) ? &As[0][0] : &Bs[0][0]) + (wid & 1) * 64 * 32;
#pragma unroll
    for (int i = 0; i < 4; ++i)
      gl_lds16(src + (size_t)(rbase + i * 16 + lrow) * K + k0 + lcolb, dst + (i * 16) * 32);
    __syncthreads();

    f16x8 a[4];
#pragma unroll
    for (int fi = 0; fi < 4; ++fi)
      a[fi] = *(const f16x8*)&As[wr * 64 + fi * 16 + fr][fk * 8];
#pragma unroll
    for (int fj = 0; fj < 4; ++fj) {
      f16x8 b = *(const f16x8*)&Bs[wc * 64 + fj * 16 + fr][fk * 8];
#pragma unroll
      for (int fi = 0; fi < 4; ++fi)
        acc[fi][fj] = __builtin_amdgcn_mfma_f32_16x16x32_f16(a[fi], b, acc[fi][fj], 0, 0, 0);
    }
    __syncthreads();
  }

#pragma unroll
  for (int fi = 0; fi < 4; ++fi)
#pragma unroll
    for (int fj = 0; fj < 4; ++fj)
#pragma unroll
      for (int r = 0; r < 4; ++r) {
        int m = m0 + wr * 64 + fi * 16 + fk * 4 + r;
        int n = n0 + wc * 64 + fj * 16 + fr;
        float y = acc[fi][fj][r];
        if (EPI == 1 || EPI == 2) y += bias[n];
        if (EPI == 2) y = fmaxf(y, 0.f);
        if (EPI == 2 || EPI == 4) Ch[(size_t)m * N + n] = f2h(y);
        else                      C[(size_t)m * N + n] = y;
      }
}

// ---------------- weight prep ------------------------------------------
// W [K][N] fp32 -> o [N][K] fp16 (transpose + cast)
__global__ __launch_bounds__(256) void tcast_k(const float* __restrict__ W,
                                               u16* __restrict__ o, int K, int N) {
  __shared__ float t[32][33];
  int kb = blockIdx.x * 32, nb = blockIdx.y * 32;
  int tx = threadIdx.x & 31, ty = threadIdx.x >> 5;
#pragma unroll
  for (int r = 0; r < 32; r += 8)
    t[ty + r][tx] = W[(size_t)(kb + ty + r) * N + nb + tx];
  __syncthreads();
#pragma unroll
  for (int r = 0; r < 32; r += 8)
    o[(size_t)(nb + ty + r) * K + kb + tx] = f2h(t[tx][ty + r]);
}

// straight cast fp32 -> fp16, 4/thread
__global__ __launch_bounds__(256) void cast4h_k(const float* __restrict__ x,
                                                u16* __restrict__ o, int n4) {
  int id = blockIdx.x * 256 + threadIdx.x;
  if (id >= n4) return;
  float4 v = *reinterpret_cast<const float4*>(&x[id * 4]);
  u16 t[4] = {f2h(v.x), f2h(v.y), f2h(v.z), f2h(v.w)};
  *reinterpret_cast<uint2*>(&o[id * 4]) = *reinterpret_cast<uint2*>(t);
}

// ---------------- embedding gather (+fp16 copy) --------------------------
__global__ __launch_bounds__(256) void gather_k(const int* __restrict__ idx,
                                                const float* __restrict__ emb,
                                                float* __restrict__ h,
                                                u16* __restrict__ hh) {
  int t = blockIdx.x, tid = threadIdx.x;
  int row = idx[t];
  if (tid < 192) {
    float4 v = *reinterpret_cast<const float4*>(&emb[(size_t)row * DM_ + tid * 4]);
    *reinterpret_cast<float4*>(&h[(size_t)t * DM_ + tid * 4]) = v;
    u16 o[4] = {f2h(v.x), f2h(v.y), f2h(v.z), f2h(v.w)};
    *reinterpret_cast<uint2*>(&hh[(size_t)t * DM_ + tid * 4]) = *reinterpret_cast<uint2*>(o);
  }
}

// ---------------- positional embedding (fp16) ----------------------------
__global__ __launch_bounds__(256) void posemb16_k(u16* __restrict__ r) {
  int u = blockIdx.x, tid = threadIdx.x;
  float pos = (float)(S_ - u);
  for (int d = tid; d < DM_; d += 256) {
    int kidx = d < 384 ? d : d - 384;
    float invf = expf(-(float)kidx * (9.210340371976184f / 384.0f));
    float arg = pos * invf;
    r[(size_t)u * DM_ + d] = f2h((d < 384) ? sinf(arg) : cosf(arg));
  }
}

// ---------------- ef[t,n,s] = (q+r_s_bias).seg_embed ---------------------
__global__ __launch_bounds__(256) void ef_k(const u16* __restrict__ qh,
                                            const float* __restrict__ rsb,
                                            const float* __restrict__ segemb,
                                            float* __restrict__ ef, int layer) {
  int id = blockIdx.x * 256 + threadIdx.x;
  int t = id / 24, rem = id % 24, n = rem >> 1, s = rem & 1;
  const u16* qp = qh + (size_t)t * DM_ + n * DH_;
  const float* rp = rsb + ((size_t)layer * NH_ + n) * DH_;
  const float* sp = segemb + (((size_t)layer * 2 + s) * NH_ + n) * DH_;
  float acc = 0.f;
#pragma unroll
  for (int d = 0; d < DH_; ++d) acc = fmaf(h2f(qp[d]) + rp[d], sp[d], acc);
  ef[id] = acc;
}

// ---------------- MFMA attention scores ----------------------------------
// sc[bn][i][j] fp16. ac = (q+rwb).k  (MFMA), bd = (q+rrb).kr window (MFMA)
__global__ __launch_bounds__(256) void score2_k(
    const u16* __restrict__ qh, const u16* __restrict__ kh,
    const u16* __restrict__ krh, const float* __restrict__ efb,
    const int* __restrict__ seg,
    const float* __restrict__ rwb_all, const float* __restrict__ rrb_all,
    u16* __restrict__ sc, int layer) {
  const int jb = blockIdx.x, ib = blockIdx.y, bn = blockIdx.z;
  const int b = bn / NH_, n = bn % NH_;
  const int i0 = ib * 64, j0 = jb * 64;
  const int tid = threadIdx.x;
  u16* out = sc + ((size_t)bn * S_ + i0) * S_ + j0;

  if (jb > ib) {  // fully masked tile -> -inf (fp16 0xFC00)
    uint4 neg = make_uint4(0xFC00FC00u, 0xFC00FC00u, 0xFC00FC00u, 0xFC00FC00u);
#pragma unroll
    for (int rep = 0; rep < 2; ++rep) {
      int f = tid + rep * 256;
      int row = f >> 3, c = (f & 7) * 8;
      *reinterpret_cast<uint4*>(&out[(size_t)row * S_ + c]) = neg;
    }
    return;
  }

  __shared__ u16 qw_s[64][72];   // q + r_w_bias
  __shared__ u16 qr_s[64][72];   // q + r_r_bias
  __shared__ u16 k_s[64][72];
  __shared__ u16 kr_s[128][72];
  __shared__ float bd_s[64][132];
  __shared__ float ef_s[64][2];
  __shared__ int segi_s[64], segj_s[64];

  {
    const int row = tid >> 2, c16 = (tid & 3) * 16;
    // q tile + biases
    const u16* qrow = qh + ((size_t)(i0 + row) * B_ + b) * DM_ + n * DH_ + c16;
    uint4 v0 = *reinterpret_cast<const uint4*>(qrow);
    uint4 v1 = *reinterpret_cast<const uint4*>(qrow + 8);
    u16 tmp[16];
    *reinterpret_cast<uint4*>(tmp) = v0;
    *reinterpret_cast<uint4*>(tmp + 8) = v1;
    const float* rwp = rwb_all + ((size_t)layer * NH_ + n) * DH_ + c16;
    const float* rrp = rrb_all + ((size_t)layer * NH_ + n) * DH_ + c16;
    u16 ow[16], orr[16];
#pragma unroll
    for (int e = 0; e < 16; ++e) {
      float f = h2f(tmp[e]);
      ow[e]  = f2h(f + rwp[e]);
      orr[e] = f2h(f + rrp[e]);
    }
    *reinterpret_cast<uint4*>(&qw_s[row][c16])     = *reinterpret_cast<uint4*>(ow);
    *reinterpret_cast<uint4*>(&qw_s[row][c16 + 8]) = *reinterpret_cast<uint4*>(ow + 8);
    *reinterpret_cast<uint4*>(&qr_s[row][c16])     = *reinterpret_cast<uint4*>(orr);
    *reinterpret_cast<uint4*>(&qr_s[row][c16 + 8]) = *reinterpret_cast<uint4*>(orr + 8);
    // k tile (straight copy)
    const u16* krow = kh + ((size_t)(j0 + row) * B_ + b) * DM_ + n * DH_ + c16;
    *reinterpret_cast<uint4*>(&k_s[row][c16])     = *reinterpret_cast<const uint4*>(krow);
    *reinterpret_cast<uint4*>(&k_s[row][c16 + 8]) = *reinterpret_cast<const uint4*>(krow + 8);
  }
  const int ubase = S_ + j0 - i0 - 63;   // in [1, 449]
  {
    const int row = tid >> 1, c32 = (tid & 1) * 32;
    const u16* krw = krh + (size_t)(ubase + row) * DM_ + n * DH_ + c32;
#pragma unroll
    for (int e = 0; e < 4; ++e)
      *reinterpret_cast<uint4*>(&kr_s[row][c32 + e * 8]) =
          *reinterpret_cast<const uint4*>(krw + e * 8);
  }
  if (tid < 128) {
    int i = tid >> 1, s = tid & 1;
    ef_s[i][s] = efb[(((size_t)(i0 + i) * B_ + b) * NH_ + n) * 2 + s];
  } else if (tid < 192) {
    segi_s[tid - 128] = seg[(i0 + tid - 128) * B_ + b];
  } else {
    segj_s[tid - 192] = seg[(j0 + tid - 192) * B_ + b];
  }
  __syncthreads();

  const int wv = tid >> 6, lane = tid & 63;
  const int lr = lane & 15, lk = lane >> 4;

  f16x8 aw[2], ar[2];
#pragma unroll
  for (int ks = 0; ks < 2; ++ks) {
    aw[ks] = *(const f16x8*)&qw_s[wv * 16 + lr][lk * 8 + ks * 32];
    ar[ks] = *(const f16x8*)&qr_s[wv * 16 + lr][lk * 8 + ks * 32];
  }
  f32x4 acc_ac[4], acc_bd[8];
#pragma unroll
  for (int fj = 0; fj < 4; ++fj)
#pragma unroll
    for (int r = 0; r < 4; ++r) acc_ac[fj][r] = 0.f;
#pragma unroll
  for (int fu = 0; fu < 8; ++fu)
#pragma unroll
    for (int r = 0; r < 4; ++r) acc_bd[fu][r] = 0.f;

#pragma unroll
  for (int ks = 0; ks < 2; ++ks) {
#pragma unroll
    for (int fj = 0; fj < 4; ++fj) {
      f16x8 bfr = *(const f16x8*)&k_s[fj * 16 + lr][lk * 8 + ks * 32];
      acc_ac[fj] = __builtin_amdgcn_mfma_f32_16x16x32_f16(aw[ks], bfr, acc_ac[fj], 0, 0, 0);
    }
#pragma unroll
    for (int fu = 0; fu < 8; ++fu) {
      f16x8 bfr = *(const f16x8*)&kr_s[fu * 16 + lr][lk * 8 + ks * 32];
      acc_bd[fu] = __builtin_amdgcn_mfma_f32_16x16x32_f16(ar[ks], bfr, acc_bd[fu], 0, 0, 0);
    }
  }
  // scatter bd fragments to LDS for the rel-shift gather
#pragma unroll
  for (int fu = 0; fu < 8; ++fu)
#pragma unroll
    for (int r = 0; r < 4; ++r)
      bd_s[wv * 16 + lk * 4 + r][fu * 16 + lr] = acc_bd[fu][r];
  __syncthreads();

  const float scale = 0.125f;
#pragma unroll
  for (int fj = 0; fj < 4; ++fj)
#pragma unroll
    for (int r = 0; r < 4; ++r) {
      int i = wv * 16 + lk * 4 + r;
      int j = fj * 16 + lr;
      int gi = i0 + i, gj = j0 + j;
      u16 o;
      if (gj > gi) {
        o = 0xFC00u;  // -inf
      } else {
        int uloc = j - i + 63;
        int s = (segi_s[i] != segj_s[j]) ? 1 : 0;
        float val = (acc_ac[fj][r] + bd_s[i][uloc] + ef_s[i][s]) * scale;
        o = f2h(val);
      }
      out[(size_t)i * S_ + j] = o;
    }
}

// ---------------- softmax over j (fp16 in, fp16 P out) -------------------
__global__ __launch_bounds__(256) void softmax2_k(const u16* __restrict__ sc,
                                                  u16* __restrict__ ph) {
  int i = blockIdx.x, bn = blockIdx.y;
  const u16* row = sc + ((size_t)bn * S_ + i) * S_;
  u16* prow = ph + ((size_t)bn * S_ + i) * S_;
  int tid = threadIdx.x;
  unsigned v = *reinterpret_cast<const unsigned*>(&row[tid * 2]);
  float x0 = h2f((u16)(v & 0xffff)), x1 = h2f((u16)(v >> 16));
  __shared__ float red[8];
  float m = fmaxf(x0, x1);
#pragma unroll
  for (int off = 32; off >= 1; off >>= 1) m = fmaxf(m, __shfl_xor(m, off));
  if ((tid & 63) == 0) red[tid >> 6] = m;
  __syncthreads();
  float M4 = fmaxf(fmaxf(red[0], red[1]), fmaxf(red[2], red[3]));
  float e0 = expf(x0 - M4), e1 = expf(x1 - M4);
  float s = e0 + e1;
#pragma unroll
  for (int off = 32; off >= 1; off >>= 1) s += __shfl_xor(s, off);
  if ((tid & 63) == 0) red[4 + (tid >> 6)] = s;
  __syncthreads();
  float inv = 1.0f / (red[4] + red[5] + red[6] + red[7]);
  unsigned o = (unsigned)f2h(e0 * inv) | ((unsigned)f2h(e1 * inv) << 16);
  *reinterpret_cast<unsigned*>(&prow[tid * 2]) = o;
}

// ---------------- MFMA PV: av[i,d] = sum_j P[i,j] V[j,d] -----------------
__global__ __launch_bounds__(256) void pv2_k(const u16* __restrict__ ph,
                                             const u16* __restrict__ vh,
                                             u16* __restrict__ avh) {
  const int ib = blockIdx.x, bn = blockIdx.y;
  const int b = bn / NH_, n = bn % NH_;
  const int i0 = ib * 64;
  const int tid = threadIdx.x;
  const int wv = tid >> 6, lane = tid & 63;
  const int lr = lane & 15, lk = lane >> 4;
  __shared__ u16 vt_s[64][72];   // [d][j]

  f32x4 acc[4];
#pragma unroll
  for (int fd = 0; fd < 4; ++fd)
#pragma unroll
    for (int r = 0; r < 4; ++r) acc[fd][r] = 0.f;

  for (int jb = 0; jb <= ib; ++jb) {
    int j0 = jb * 64;
    {
      const int jr = tid >> 2, c16 = (tid & 3) * 16;
      const u16* vrow = vh + ((size_t)(j0 + jr) * B_ + b) * DM_ + n * DH_ + c16;
      u16 tmp[16];
      *reinterpret_cast<uint4*>(tmp)     = *reinterpret_cast<const uint4*>(vrow);
      *reinterpret_cast<uint4*>(tmp + 8) = *reinterpret_cast<const uint4*>(vrow + 8);
#pragma unroll
      for (int e = 0; e < 16; ++e) vt_s[c16 + e][jr] = tmp[e];
    }
    __syncthreads();
    const u16* prow = ph + ((size_t)bn * S_ + i0 + wv * 16 + lr) * S_ + j0;
    f16x8 afr[2];
    afr[0] = *(const f16x8*)(prow + lk * 8);
    afr[1] = *(const f16x8*)(prow + 32 + lk * 8);
#pragma unroll
    for (int ks = 0; ks < 2; ++ks)
#pragma unroll
      for (int fd = 0; fd < 4; ++fd) {
        f16x8 bfr = *(const f16x8*)&vt_s[fd * 16 + lr][lk * 8 + ks * 32];
        acc[fd] = __builtin_amdgcn_mfma_f32_16x16x32_f16(afr[ks], bfr, acc[fd], 0, 0, 0);
      }
    __syncthreads();
  }
#pragma unroll
  for (int fd = 0; fd < 4; ++fd)
#pragma unroll
    for (int r = 0; r < 4; ++r) {
      int i = i0 + wv * 16 + lk * 4 + r;
      int d = fd * 16 + lr;
      avh[((size_t)i * B_ + b) * DM_ + n * DH_ + d] = f2h(acc[fd][r]);
    }
}

// ---------------- residual + LayerNorm (+fp16 copy) ----------------------
__global__ __launch_bounds__(256) void add_ln_k(const float* __restrict__ a,
                                                const float* __restrict__ bb,
                                                float* __restrict__ out,
                                                u16* __restrict__ oh,
                                                const float* __restrict__ g,
                                                const float* __restrict__ beta) {
  int t = blockIdx.x, tid = threadIdx.x;
  const float* ap = a + (size_t)t * DM_;
  const float* bp = bb + (size_t)t * DM_;
  float x[3];
  float s1 = 0.f, s2 = 0.f;
#pragma unroll
  for (int j = 0; j < 3; ++j) {
    int d = tid + j * 256;
    x[j] = ap[d] + bp[d];
    s1 += x[j];
    s2 += x[j] * x[j];
  }
  __shared__ float r1[4], r2[4];
#pragma unroll
  for (int off = 32; off >= 1; off >>= 1) {
    s1 += __shfl_xor(s1, off);
    s2 += __shfl_xor(s2, off);
  }
  if ((tid & 63) == 0) { r1[tid >> 6] = s1; r2[tid >> 6] = s2; }
  __syncthreads();
  float S1 = r1[0] + r1[1] + r1[2] + r1[3];
  float S2 = r2[0] + r2[1] + r2[2] + r2[3];
  float mu = S1 * (1.0f / 768.0f);
  float var = S2 * (1.0f / 768.0f) - mu * mu;
  float rstd = rsqrtf(var + 1e-5f);
  float* op = out + (size_t)t * DM_;
#pragma unroll
  for (int j = 0; j < 3; ++j) {
    int d = tid + j * 256;
    float y = (x[j] - mu) * rstd * g[d] + beta[d];
    op[d] = y;
    oh[(size_t)t * DM_ + d] = f2h(y);
  }
}

// ---------------- launch ------------------------------------------------
extern "C" void kernel_launch(void* const* d_in, const int* in_sizes, int n_in,
                              void* d_out, int out_size, void* d_ws, size_t ws_size,
                              hipStream_t stream) {
  const int*   inp_k    = (const int*)d_in[0];
  const int*   seg_id   = (const int*)d_in[1];
  const float* emb      = (const float*)d_in[2];
  const float* Wq       = (const float*)d_in[3];
  const float* Wk       = (const float*)d_in[4];
  const float* Wv       = (const float*)d_in[5];
  const float* Wr       = (const float*)d_in[6];
  const float* proj_o   = (const float*)d_in[7];
  const float* r_w_bias = (const float*)d_in[8];
  const float* r_r_bias = (const float*)d_in[9];
  const float* r_s_bias = (const float*)d_in[10];
  const float* seg_emb  = (const float*)d_in[11];
  const float* ln_g     = (const float*)d_in[12];
  const float* ln_b     = (const float*)d_in[13];
  const float* W1       = (const float*)d_in[14];
  const float* b1       = (const float*)d_in[15];
  const float* W2       = (const float*)d_in[16];
  const float* b2       = (const float*)d_in[17];
  const float* smax_b   = (const float*)d_in[18];
  float* out = (float*)d_out;

  float* ws  = (float*)d_ws;
  float* h   = ws;                                  // 2048*768 f32
  float* ao  = h  + (size_t)M_ * DM_;               // 2048*768 f32
  float* efb = ao + (size_t)M_ * DM_;               // 2048*24 f32
  u16* p     = (u16*)(efb + (size_t)M_ * NH_ * 2);
  u16* sc    = p;  p += (size_t)B_ * NH_ * S_ * S_; // 12.58M
  u16* phb   = p;  p += (size_t)B_ * NH_ * S_ * S_; // 12.58M
  u16* hh    = p;  p += (size_t)M_ * DM_;
  u16* qh    = p;  p += (size_t)M_ * DM_;
  u16* kh    = p;  p += (size_t)M_ * DM_;
  u16* vh    = p;  p += (size_t)M_ * DM_;
  u16* avh   = p;  p += (size_t)M_ * DM_;
  u16* midh  = p;  p += (size_t)M_ * DI_;
  u16* krh   = p;  p += (size_t)2 * S_ * DM_;
  u16* rh    = p;  p += (size_t)2 * S_ * DM_;
  u16* embh  = p;  p += (size_t)V_ * DM_;
  u16* wqh   = p;  p += (size_t)DM_ * DM_;
  u16* wkh   = p;  p += (size_t)DM_ * DM_;
  u16* wvh   = p;  p += (size_t)DM_ * DM_;
  u16* wrh   = p;  p += (size_t)DM_ * DM_;
  u16* poh   = p;  p += (size_t)DM_ * DM_;
  u16* w1h   = p;  p += (size_t)DM_ * DI_;
  u16* w2h   = p;  p += (size_t)DM_ * DI_;

  // ---- prep ----
  gather_k<<<M_, 256, 0, stream>>>(inp_k, emb, h, hh);
  posemb16_k<<<2 * S_, 256, 0, stream>>>(rh);
  tcast_k<<<dim3(DM_ / 32, DM_ / 32), 256, 0, stream>>>(Wq, wqh, DM_, DM_);
  tcast_k<<<dim3(DM_ / 32, DM_ / 32), 256, 0, stream>>>(Wk, wkh, DM_, DM_);
  tcast_k<<<dim3(DM_ / 32, DM_ / 32), 256, 0, stream>>>(Wv, wvh, DM_, DM_);
  tcast_k<<<dim3(DM_ / 32, DM_ / 32), 256, 0, stream>>>(Wr, wrh, DM_, DM_);
  tcast_k<<<dim3(DM_ / 32, DI_ / 32), 256, 0, stream>>>(W1, w1h, DM_, DI_);
  tcast_k<<<dim3(DI_ / 32, DM_ / 32), 256, 0, stream>>>(W2, w2h, DI_, DM_);
  cast4h_k<<<(DM_ * DM_ / 4 + 255) / 256, 256, 0, stream>>>(proj_o, poh, DM_ * DM_ / 4);
  cast4h_k<<<(V_ * DM_ / 4 + 255) / 256, 256, 0, stream>>>(emb, embh, V_ * DM_ / 4);
  // kr = r . Wr^T  -> fp16
  mg16_k<4><<<dim3((2 * S_) / 128, DM_ / 128), 256, 0, stream>>>(rh, wrh, nullptr, nullptr, krh, 2 * S_, DM_, DM_);

  for (int l = 0; l < 4; ++l) {
    mg16_k<4><<<dim3(M_ / 128, DM_ / 128), 256, 0, stream>>>(hh, wqh, nullptr, nullptr, qh, M_, DM_, DM_);
    mg16_k<4><<<dim3(M_ / 128, DM_ / 128), 256, 0, stream>>>(hh, wkh, nullptr, nullptr, kh, M_, DM_, DM_);
    mg16_k<4><<<dim3(M_ / 128, DM_ / 128), 256, 0, stream>>>(hh, wvh, nullptr, nullptr, vh, M_, DM_, DM_);
    ef_k<<<(M_ * NH_ * 2) / 256, 256, 0, stream>>>(qh, r_s_bias, seg_emb, efb, l);
    score2_k<<<dim3(8, 8, B_ * NH_), 256, 0, stream>>>(qh, kh, krh, efb, seg_id, r_w_bias, r_r_bias, sc, l);
    softmax2_k<<<dim3(S_, B_ * NH_), 256, 0, stream>>>(sc, phb);
    pv2_k<<<dim3(8, B_ * NH_), 256, 0, stream>>>(phb, vh, avh);
    mg16_k<0><<<dim3(M_ / 128, DM_ / 128), 256, 0, stream>>>(avh, poh, nullptr, ao, nullptr, M_, DM_, DM_);
    add_ln_k<<<M_, 256, 0, stream>>>(ao, h, h, hh, ln_g, ln_b);
    mg16_k<2><<<dim3(M_ / 128, DI_ / 128), 256, 0, stream>>>(hh, w1h, b1, nullptr, midh, M_, DI_, DM_);
    mg16_k<1><<<dim3(M_ / 128, DM_ / 128), 256, 0, stream>>>(midh, w2h, b2, ao, nullptr, M_, DM_, DI_);
    add_ln_k<<<M_, 256, 0, stream>>>(ao, h, h, hh, ln_g, ln_b);
  }

  // ---- logits: out = hh . embh^T + smax_b ----
  mg16_k<1><<<dim3(M_ / 128, V_ / 128), 256, 0, stream>>>(hh, embh, smax_b, out, nullptr, M_, V_, DM_);
}